// Round 1
// baseline (380.264 us; speedup 1.0000x reference)
//
#include <hip/hip_runtime.h>
#include <hip/hip_bf16.h>
#include <cstdint>
#include <type_traits>

using bf16_t = __hip_bfloat16;
typedef __bf16 bf16x8 __attribute__((ext_vector_type(8)));
typedef float f32x4 __attribute__((ext_vector_type(4)));

// ---------------- f32 -> bf16 convert, 8 elems/thread ----------------
__global__ void cvt_f32_to_bf16(const float* __restrict__ in, bf16_t* __restrict__ out, int n8) {
  int stride = gridDim.x * blockDim.x;
  for (int i = blockIdx.x * blockDim.x + threadIdx.x; i < n8; i += stride) {
    const float4* p = reinterpret_cast<const float4*>(in) + (size_t)i * 2;
    float4 a = p[0];
    float4 b = p[1];
    bf16_t o[8];
    o[0] = __float2bfloat16(a.x); o[1] = __float2bfloat16(a.y);
    o[2] = __float2bfloat16(a.z); o[3] = __float2bfloat16(a.w);
    o[4] = __float2bfloat16(b.x); o[5] = __float2bfloat16(b.y);
    o[6] = __float2bfloat16(b.z); o[7] = __float2bfloat16(b.w);
    *reinterpret_cast<uint4*>(out + (size_t)i * 8) = *reinterpret_cast<const uint4*>(o);
  }
}

// ---------------- bf16 GEMM: C[M,N] = A[M,K] * Bt[N,K]^T ----------------
// 128x128 tile, BK=32, 4 waves (2x2 of 64x64), mfma_f32_16x16x32_bf16.
template <typename OutT>
__global__ __launch_bounds__(256) void gemm_bt(const bf16_t* __restrict__ A,
                                               const bf16_t* __restrict__ Bt,
                                               OutT* __restrict__ C,
                                               int M, int N, int K) {
  __shared__ __align__(16) bf16_t As[128 * 32];
  __shared__ __align__(16) bf16_t Bs[128 * 32];
  const int tid = threadIdx.x;
  const int lane = tid & 63;
  const int w = tid >> 6;
  const int wm = w >> 1, wn = w & 1;
  const int lr = lane & 15, lc = lane >> 4;
  const int m0 = blockIdx.y * 128, n0 = blockIdx.x * 128;

  // staging chunks: chunk c covers row c>>2, cols (c&3)*8 .. +8 (16B)
  const int c0 = tid, c1 = tid + 256;
  const bf16_t* a0p = A + (size_t)(m0 + (c0 >> 2)) * K + (c0 & 3) * 8;
  const bf16_t* a1p = A + (size_t)(m0 + (c1 >> 2)) * K + (c1 & 3) * 8;
  const bf16_t* b0p = Bt + (size_t)(n0 + (c0 >> 2)) * K + (c0 & 3) * 8;
  const bf16_t* b1p = Bt + (size_t)(n0 + (c1 >> 2)) * K + (c1 & 3) * 8;

  f32x4 acc[4][4] = {};

  uint4 ra0 = *(const uint4*)(a0p);
  uint4 ra1 = *(const uint4*)(a1p);
  uint4 rb0 = *(const uint4*)(b0p);
  uint4 rb1 = *(const uint4*)(b1p);

  for (int k0 = 0; k0 < K; k0 += 32) {
    __syncthreads();
    *(uint4*)&As[c0 * 8] = ra0;
    *(uint4*)&As[c1 * 8] = ra1;
    *(uint4*)&Bs[c0 * 8] = rb0;
    *(uint4*)&Bs[c1 * 8] = rb1;
    __syncthreads();
    if (k0 + 32 < K) {  // prefetch next tile into regs, overlaps with MFMAs below
      ra0 = *(const uint4*)(a0p + k0 + 32);
      ra1 = *(const uint4*)(a1p + k0 + 32);
      rb0 = *(const uint4*)(b0p + k0 + 32);
      rb1 = *(const uint4*)(b1p + k0 + 32);
    }
    bf16x8 af[4], bfv[4];
#pragma unroll
    for (int i = 0; i < 4; ++i)
      af[i] = *reinterpret_cast<const bf16x8*>(&As[(wm * 64 + i * 16 + lr) * 32 + lc * 8]);
#pragma unroll
    for (int i = 0; i < 4; ++i)
      bfv[i] = *reinterpret_cast<const bf16x8*>(&Bs[(wn * 64 + i * 16 + lr) * 32 + lc * 8]);
#pragma unroll
    for (int i = 0; i < 4; ++i)
#pragma unroll
      for (int j = 0; j < 4; ++j)
        acc[i][j] = __builtin_amdgcn_mfma_f32_16x16x32_bf16(af[i], bfv[j], acc[i][j], 0, 0, 0);
  }

  // epilogue: C/D layout col=lane&15, row=(lane>>4)*4+reg  [measured m89/m91]
#pragma unroll
  for (int i = 0; i < 4; ++i)
#pragma unroll
    for (int j = 0; j < 4; ++j) {
      int row = m0 + wm * 64 + i * 16 + lc * 4;
      int col = n0 + wn * 64 + j * 16 + lr;
#pragma unroll
      for (int r = 0; r < 4; ++r) {
        float v = acc[i][j][r];
        if constexpr (std::is_same<OutT, float>::value)
          C[(size_t)(row + r) * N + col] = v;
        else
          C[(size_t)(row + r) * N + col] = __float2bfloat16(v);
      }
    }
}

// ---------------- RoPE + scatter qkv -> Q (scaled), K, V ----------------
// qkv: [B*T][3072] where col = g*768 + slot*128 + d ; slots 0..3 q, 4 k, 5 v
__global__ __launch_bounds__(256) void rope_scatter(const bf16_t* __restrict__ qkv,
                                                    const float* __restrict__ cosp,
                                                    const float* __restrict__ sinp,
                                                    bf16_t* __restrict__ Q,
                                                    bf16_t* __restrict__ K,
                                                    bf16_t* __restrict__ V) {
  const int row = blockIdx.x;  // b*2048 + t
  const int b = row >> 11, t = row & 2047;
  const bf16_t* src = qkv + (size_t)row * 3072;
  for (int n = threadIdx.x; n < 3072; n += 256) {
    int g = n / 768;
    int r = n - g * 768;
    int slot = r >> 7;
    int d = r & 127;
    if (slot == 5) {
      V[(((size_t)(b * 4 + g)) * 2048 + t) * 128 + d] = src[n];
    } else {
      float v = __bfloat162float(src[n]);
      float other = __bfloat162float(src[n ^ 64]);  // bit 6 of n == bit 6 of d
      float c = cosp[t * 128 + d];
      float s = sinp[t * 128 + d];
      float rot = (d < 64) ? -other : other;
      float res = v * c + rot * s;
      if (slot < 4) {
        int h = g * 4 + slot;
        // fold softmax scale 1/sqrt(128) into Q
        Q[(((size_t)(b * 16 + h)) * 2048 + t) * 128 + d] =
            __float2bfloat16(res * 0.08838834764831843f);
      } else {
        K[(((size_t)(b * 4 + g)) * 2048 + t) * 128 + d] = __float2bfloat16(res);
      }
    }
  }
}

// ---------------- V [bg][t][d] -> Vt [bg][d][t] ----------------
__global__ void transpose_v(const bf16_t* __restrict__ V, bf16_t* __restrict__ Vt) {
  __shared__ bf16_t tile[32][33];
  const int bg = blockIdx.z;
  const int t0 = blockIdx.x * 32;
  const int d0 = blockIdx.y * 32;
  const bf16_t* src = V + (size_t)bg * 2048 * 128;
  bf16_t* dst = Vt + (size_t)bg * 128 * 2048;
#pragma unroll
  for (int i = threadIdx.y; i < 32; i += 8)
    tile[i][threadIdx.x] = src[(size_t)(t0 + i) * 128 + d0 + threadIdx.x];
  __syncthreads();
#pragma unroll
  for (int i = threadIdx.y; i < 32; i += 8)
    dst[(size_t)(d0 + i) * 2048 + t0 + threadIdx.x] = tile[threadIdx.x][i];
}

// ---------------- sliding-window flash attention ----------------
// 1 wave per 16-row Q tile; K-tiles of 32; Q pre-scaled; Vt is V^T per (b,g).
// Y layout: [B][T][H][HS]  (== A matrix of the output projection)
__global__ __launch_bounds__(256) void attn_swa(const bf16_t* __restrict__ Q,
                                                const bf16_t* __restrict__ K,
                                                const bf16_t* __restrict__ Vt,
                                                bf16_t* __restrict__ Y) {
  const int tid = threadIdx.x;
  const int lane = tid & 63;
  const int w = tid >> 6;
  const int lr = lane & 15, lc = lane >> 4;
  const int b = blockIdx.z, h = blockIdx.y;
  const int qt = blockIdx.x * 4 + w;
  const int i0 = qt * 16;
  const int g = h >> 2;

  const bf16_t* Qp = Q + ((size_t)(b * 16 + h) * 2048) * 128;
  const bf16_t* Kp = K + ((size_t)(b * 4 + g) * 2048) * 128;
  const bf16_t* Vp = Vt + ((size_t)(b * 4 + g) * 128) * 2048;

  __shared__ __align__(16) bf16_t P_lds[4][16 * 32];

  bf16x8 qf[4];
#pragma unroll
  for (int kc = 0; kc < 4; ++kc)
    qf[kc] = *reinterpret_cast<const bf16x8*>(&Qp[(size_t)(i0 + lr) * 128 + kc * 32 + lc * 8]);

  f32x4 o[8] = {};
  float mrow[4] = {-1e30f, -1e30f, -1e30f, -1e30f};
  float lsum[4] = {0.f, 0.f, 0.f, 0.f};

  int jlo = i0 - 1023;
  if (jlo < 0) jlo = 0;
  const int j0s = jlo & ~31;

  for (int j0 = j0s; j0 <= i0 + 15; j0 += 32) {
    f32x4 s0 = {}, s1 = {};
#pragma unroll
    for (int kc = 0; kc < 4; ++kc) {
      bf16x8 kf0 = *reinterpret_cast<const bf16x8*>(&Kp[(size_t)(j0 + lr) * 128 + kc * 32 + lc * 8]);
      bf16x8 kf1 = *reinterpret_cast<const bf16x8*>(&Kp[(size_t)(j0 + 16 + lr) * 128 + kc * 32 + lc * 8]);
      s0 = __builtin_amdgcn_mfma_f32_16x16x32_bf16(qf[kc], kf0, s0, 0, 0, 0);
      s1 = __builtin_amdgcn_mfma_f32_16x16x32_bf16(qf[kc], kf1, s1, 0, 0, 0);
    }
    float alpha[4];
#pragma unroll
    for (int r = 0; r < 4; ++r) {
      int i = i0 + lc * 4 + r;
      int ja = j0 + lr, jb = j0 + 16 + lr;
      bool oka = (ja <= i) && (ja > i - 1024);
      bool okb = (jb <= i) && (jb > i - 1024);
      float sa = oka ? s0[r] : -1e30f;
      float sb = okb ? s1[r] : -1e30f;
      float rm = fmaxf(sa, sb);
#pragma unroll
      for (int off = 8; off; off >>= 1) rm = fmaxf(rm, __shfl_xor(rm, off, 16));
      float mnew = fmaxf(mrow[r], rm);
      alpha[r] = __expf(mrow[r] - mnew);
      mrow[r] = mnew;
      // explicit mask on p: fully-masked tiles must contribute exactly 0
      float pa = oka ? __expf(sa - mnew) : 0.f;
      float pb = okb ? __expf(sb - mnew) : 0.f;
      float ps = pa + pb;
#pragma unroll
      for (int off = 8; off; off >>= 1) ps += __shfl_xor(ps, off, 16);
      lsum[r] = lsum[r] * alpha[r] + ps;
      P_lds[w][(lc * 4 + r) * 32 + lr] = __float2bfloat16(pa);
      P_lds[w][(lc * 4 + r) * 32 + 16 + lr] = __float2bfloat16(pb);
    }
#pragma unroll
    for (int f = 0; f < 8; ++f)
#pragma unroll
      for (int r = 0; r < 4; ++r) o[f][r] *= alpha[r];
    // wave-local LDS write->read: drain LDS queue (lockstep wave, no barrier needed)
    asm volatile("s_waitcnt lgkmcnt(0)" ::: "memory");
    bf16x8 pfrag = *reinterpret_cast<const bf16x8*>(&P_lds[w][lr * 32 + lc * 8]);
#pragma unroll
    for (int f = 0; f < 8; ++f) {
      bf16x8 vf = *reinterpret_cast<const bf16x8*>(&Vp[(size_t)(f * 16 + lr) * 2048 + j0 + lc * 8]);
      o[f] = __builtin_amdgcn_mfma_f32_16x16x32_bf16(pfrag, vf, o[f], 0, 0, 0);
    }
  }

#pragma unroll
  for (int r = 0; r < 4; ++r) {
    int i = i0 + lc * 4 + r;
    float inv = 1.f / lsum[r];
#pragma unroll
    for (int f = 0; f < 8; ++f)
      Y[((size_t)(b * 2048 + i)) * 2048 + h * 128 + f * 16 + lr] =
          __float2bfloat16(o[f][r] * inv);
  }
}

// ---------------- launch ----------------
extern "C" void kernel_launch(void* const* d_in, const int* in_sizes, int n_in,
                              void* d_out, int out_size, void* d_ws, size_t ws_size,
                              hipStream_t stream) {
  const float* x = (const float*)d_in[0];
  const float* cosp = (const float*)d_in[1];
  const float* sinp = (const float*)d_in[2];
  const float* Wa = (const float*)d_in[3];
  const float* Wp = (const float*)d_in[4];
  float* out = (float*)d_out;

  bf16_t* ws = (bf16_t*)d_ws;
  // live ranges allow aliasing: total 62,914,560 bytes of ws
  bf16_t* xb = ws;                  // 8388608  (x bf16)           -> reused as Q
  bf16_t* wab = ws + 8388608;       // 6291456  (W_attn bf16)      -> reused as K,V
  bf16_t* wpb = ws + 14680064;      // 4194304  (W_proj bf16)
  bf16_t* qkv = ws + 18874368;      // 12582912 (qkv bf16)         -> reused as Y,Vt
  bf16_t* Q = xb;                   // 8388608  [B][H][T][HS]
  bf16_t* Kr = wab;                 // 2097152  [B][G][T][HS]
  bf16_t* V = wab + 2097152;        // 2097152  [B][G][T][HS]
  bf16_t* Y = qkv;                  // 8388608  [B][T][H][HS]
  bf16_t* Vt = qkv + 8388608;       // 2097152  [B][G][HS][T]

  cvt_f32_to_bf16<<<4096, 256, 0, stream>>>(x, xb, 1048576);
  cvt_f32_to_bf16<<<3072, 256, 0, stream>>>(Wa, wab, 786432);
  cvt_f32_to_bf16<<<2048, 256, 0, stream>>>(Wp, wpb, 524288);

  // qkv = xb @ wab^T : M=4096 N=3072 K=2048
  gemm_bt<bf16_t><<<dim3(24, 32), 256, 0, stream>>>(xb, wab, qkv, 4096, 3072, 2048);

  rope_scatter<<<4096, 256, 0, stream>>>(qkv, cosp, sinp, Q, Kr, V);

  transpose_v<<<dim3(64, 4, 8), dim3(32, 8), 0, stream>>>(V, Vt);

  attn_swa<<<dim3(32, 16, 2), 256, 0, stream>>>(Q, Kr, Vt, Y);

  // out = Y @ wpb^T : M=4096 N=2048 K=2048 (f32 out)
  gemm_bt<float><<<dim3(16, 32), 256, 0, stream>>>(Y, wpb, out, 4096, 2048, 2048);
}